// Round 14
// baseline (362.580 us; speedup 1.0000x reference)
//
#include <hip/hip_runtime.h>
#include <stdint.h>

#define NN 8192
#define K_ORD 262144u      // ordered top-k positions (off-diagonal, both triangles)
#define CH_CAP 2048

// ws layout (uint32 words):
// [0..3071]    partial counts: round r (1..3) block bx writes [(r-1)*1024 + bx]
//              (bx = probe*4 + quarter; per-probe count = sum of its 4 slots)
// [4096] hi  [4097] lo  [4098] r(=nch)  [4099..4103] pad
// [4104..12295]  sorted p values (8192 floats, desc by key)
// [12296..20487] orig index per sorted slot (perm)
// [20488..22535] chosen tie flat-indices, compacted by rank (exactly r entries)
#define WS_HI 4096
#define WS_LO 4097
#define WS_R 4098
#define WS_STATE0 4096
#define WS_STATEN 8
#define WS_SORT 4104
#define WS_IDX 12296
#define WS_CH 20488

__device__ __forceinline__ uint32_t fkey(float x) {
    // order-preserving map float -> uint32 (neg: ~u, pos: u|0x80000000)
    uint32_t u = __float_as_uint(x);
    uint32_t m = (uint32_t)((int32_t)u >> 31) | 0x80000000u;
    return u ^ m;
}
__device__ __forceinline__ float inv_fkey(uint32_t k) {
    uint32_t u = (k & 0x80000000u) ? (k ^ 0x80000000u) : ~k;
    return __uint_as_float(u);
}

// ---------------------------------------------------------------------------
// Kernel 1 (R8-verbatim + perm store): rank sort of p (desc by key, ties by
// index) -> sorted values + permutation. 1024 blocks x 256 thr.
__global__ void __launch_bounds__(256) sort_kernel(const float* __restrict__ p,
                                                   uint32_t* __restrict__ ws) {
    __shared__ uint32_t ks[NN];
    const int tx = threadIdx.x;
    if (blockIdx.x == 0 && tx < WS_STATEN) ws[WS_STATE0 + tx] = 0u;
    for (int t = tx; t < NN / 4; t += 256) {
        const float4 v = reinterpret_cast<const float4*>(p)[t];
        reinterpret_cast<uint4*>(ks)[t] =
            make_uint4(fkey(v.x), fkey(v.y), fkey(v.z), fkey(v.w));
    }
    __syncthreads();
    const int e = blockIdx.x * 8 + (tx >> 5);
    const int seg = tx & 31;
    const uint32_t ke = ks[e];
    uint32_t cnt = 0;
    for (int it = 0; it < 256; ++it) {
        const int j = seg + 32 * it;
        const uint32_t kj = ks[j];
        cnt += (kj > ke) ? 1u : 0u;
        cnt += (kj == ke && j < e) ? 1u : 0u;
    }
    for (int off = 16; off > 0; off >>= 1) cnt += __shfl_down(cnt, off, 32);
    if (seg == 0) {
        reinterpret_cast<float*>(ws + WS_SORT)[cnt] = inv_fkey(ke);  // unique rank
        ws[WS_IDX + cnt] = (uint32_t)e;
    }
}

// ---------------------------------------------------------------------------
// Partial f(T) over rows [a0, a0+2048): 4 INDEPENDENT interleaved 14-step
// chains per thread (ILP4; R13-proven). Search space [0,8192].
__device__ uint32_t eval_count4(const float* __restrict__ ps, uint32_t T, int a0) {
    const int a = a0 + threadIdx.x * 4;
    float pa[4];
    uint32_t neg[4];
    int pos[4] = {0, 0, 0, 0};
#pragma unroll
    for (int c = 0; c < 4; ++c) {
        pa[c] = ps[a + c];
        neg[c] = __float_as_uint(pa[c]) >> 31;
    }
#pragma unroll
    for (int st = NN; st > 0; st >>= 1) {
#pragma unroll
        for (int c = 0; c < 4; ++c) {
            const int cand = pos[c] + st;
            if (cand <= NN) {
                const uint32_t pr = (fkey(pa[c] * ps[cand - 1]) > T) ? 1u : 0u;
                if (pr ^ neg[c]) pos[c] = cand;
            }
        }
    }
    uint32_t cnt = 0;
#pragma unroll
    for (int c = 0; c < 4; ++c) {
        uint32_t cc = neg[c] ? (uint32_t)(NN - pos[c]) : (uint32_t)pos[c];
        cc -= (fkey(pa[c] * pa[c]) > T) ? 1u : 0u;   // exclude diagonal pairing
        cnt += cc;
    }
    return cnt;
}

// Recompute bracket after `rounds` completed rounds (R8-proven).
// On exit: T* in [lo,hi], fstar = f(hi) < K.
template <int NT>
__device__ void bracket_chain(const uint32_t* __restrict__ ws, int rounds,
                              uint32_t* __restrict__ sh,
                              uint32_t& lo, uint32_t& hi, uint32_t& fstar) {
    const int tx = threadIdx.x;
    lo = 0u; hi = 0xFFFFFFFFu; fstar = 0u;
    for (int r = 0; r < rounds; ++r) {
        uint32_t flag = 1024u;
        if (tx < 256) {
            uint32_t c = 0;
#pragma unroll
            for (int q = 0; q < 4; ++q)
                c += __hip_atomic_load(&ws[r * 1024 + tx * 4 + q],
                                       __ATOMIC_RELAXED, __HIP_MEMORY_SCOPE_AGENT);
            if (c < K_ORD) flag = (uint32_t)tx;
        }
        sh[tx] = flag;
        __syncthreads();
        for (int off = NT / 2; off > 0; off >>= 1) {
            if (tx < off) sh[tx] = min(sh[tx], sh[tx + off]);
            __syncthreads();
        }
        const uint32_t cs = sh[0];   // minimal c with f(T_c) < K (exists: f(hi)<K)
        __syncthreads();
        uint32_t fsum = 0;
#pragma unroll
        for (int q = 0; q < 4; ++q)
            fsum += __hip_atomic_load(&ws[r * 1024 + cs * 4 + q],
                                      __ATOMIC_RELAXED, __HIP_MEMORY_SCOPE_AGENT);
        fstar = fsum;
        const uint64_t W = (uint64_t)(hi - lo);
        const uint32_t Tc = lo + (uint32_t)(((uint64_t)(cs + 1) * W) >> 8);
        if (cs > 0) lo = lo + (uint32_t)(((uint64_t)cs * W) >> 8) + 1u;
        hi = Tc;
    }
}

// Kernels 2-4: rounds 1-3 (R13-verbatim).
template <int ROUND>
__global__ void __launch_bounds__(512) select_round_kernel(uint32_t* __restrict__ ws) {
    __shared__ float ps[NN];
    __shared__ uint32_t sh[512];
    const int tx = threadIdx.x;
    const int bx = blockIdx.x;
    for (int t = tx; t < NN / 4; t += 512)
        reinterpret_cast<float4*>(ps)[t] =
            reinterpret_cast<const float4*>(ws + WS_SORT)[t];
    __syncthreads();
    uint32_t lo, hi, fs;
    bracket_chain<512>(ws, ROUND - 1, sh, lo, hi, fs);
    const uint64_t W = (uint64_t)(hi - lo);
    const uint32_t T = lo + (uint32_t)(((uint64_t)((bx >> 2) + 1) * W) >> 8);
    const uint32_t cnt = eval_count4(ps, T, (bx & 3) * 2048);
    __syncthreads();
    sh[tx] = cnt;
    __syncthreads();
    for (int off = 256; off > 0; off >>= 1) {
        if (tx < off) sh[tx] += sh[tx + off];
        __syncthreads();
    }
    if (tx == 0) ws[(ROUND - 1) * 1024 + bx] = sh[0];   // private slot, plain store
}

// One monotone boundary search (R9-proven): for non-neg rows the key>T set is
// the prefix [0,pos); for neg rows it is the suffix [pos,NN).
__device__ __forceinline__ int searchT(const float* __restrict__ ps, float pa,
                                       uint32_t neg, uint32_t T) {
    int pos = 0;
#pragma unroll
    for (int st = NN; st > 0; st >>= 1) {
        const int cand = pos + st;
        if (cand <= NN) {
            const uint32_t pr = (fkey(pa * ps[cand - 1]) > T) ? 1u : 0u;
            if (pr ^ neg) pos = cand;
        }
    }
    return pos;
}

// Kernel 5: finalize after 3 rounds + tie enumeration + ranking, one block.
// Bracket <= 257 keys wide => in-bracket pairs ~130 (empirical 0.5/ulp), cap
// 2048 (15x margin). Ranks are unique => every rank in [0,r) written exactly
// once => chosen list needs no zeroing.
__global__ void __launch_bounds__(512) finalize_enum_kernel(uint32_t* __restrict__ ws) {
    __shared__ float ps[NN];
    __shared__ uint32_t sh[512];
    __shared__ uint32_t tkey[CH_CAP];
    __shared__ uint32_t tflat[CH_CAP];
    __shared__ uint32_t tcnt;
    const int tx = threadIdx.x;
    for (int t = tx; t < NN / 4; t += 512)
        reinterpret_cast<float4*>(ps)[t] =
            reinterpret_cast<const float4*>(ws + WS_SORT)[t];
    if (tx == 0) tcnt = 0u;
    __syncthreads();
    uint32_t lo, hi, fs;
    bracket_chain<512>(ws, 3, sh, lo, hi, fs);
    const uint32_t r = K_ORD - fs;       // in-bracket slots to fill

    // enumerate all ordered off-diagonal pairs with lo <= key <= hi
    for (int g = 0; g < 4; ++g) {
#pragma unroll
        for (int c = 0; c < 4; ++c) {
            const int a = tx * 16 + g * 4 + c;
            const float pa = ps[a];
            const uint32_t neg = __float_as_uint(pa) >> 31;
            const int pgt = searchT(ps, pa, neg, hi);
            const int pge = (lo == 0u) ? (neg ? 0 : NN)
                                       : searchT(ps, pa, neg, lo - 1u);
            const int b0 = neg ? pge : pgt;
            const int b1 = neg ? pgt : pge;
            for (int b = b0; b < b1; ++b) {
                if (b == a) continue;
                const uint32_t slot = atomicAdd(&tcnt, 1u);
                if (slot < CH_CAP) {
                    tkey[slot] = fkey(pa * ps[b]);
                    tflat[slot] = ws[WS_IDX + a] * NN + ws[WS_IDX + b];
                }
            }
        }
    }
    __syncthreads();
    const uint32_t n = min(tcnt, (uint32_t)CH_CAP);
    // chosen = top r by (key desc, flat idx asc) — jax.lax.top_k's ordering
    for (uint32_t e = tx; e < n; e += 512) {
        const uint32_t mk = tkey[e], mf = tflat[e];
        uint32_t rank = 0;
        for (uint32_t m = 0; m < n; ++m)
            rank += ((tkey[m] > mk) || (tkey[m] == mk && tflat[m] < mf)) ? 1u : 0u;
        if (rank < r) ws[WS_CH + rank] = mf;
    }
    if (tx == 0) {
        ws[WS_HI] = hi;
        ws[WS_LO] = lo;
        ws[WS_R] = r;
    }
}

// Kernel 6: streamed 268MB mask write, plain float4 stores, NO atomics.
// key > hi -> 1; lo <= key <= hi -> membership scan of the tiny chosen list.
__global__ void __launch_bounds__(256) mask_kernel(const float* __restrict__ p,
                                                   float* __restrict__ out,
                                                   uint32_t* __restrict__ ws) {
    const int tx = threadIdx.x;
    const int i = blockIdx.y;
    const int jb0 = blockIdx.x * 4096;
    const uint32_t hi = ws[WS_HI];
    const uint32_t lo = ws[WS_LO];
    const float pi = p[i];
    const size_t rowbase = (size_t)i * NN;
#pragma unroll
    for (int q = 0; q < 4; ++q) {
        const int j = jb0 + q * 1024 + tx * 4;
        const float4 pj = *reinterpret_cast<const float4*>(p + j);
        const float pjv[4] = {pj.x, pj.y, pj.z, pj.w};
        float vv[4];
#pragma unroll
        for (int c = 0; c < 4; ++c) {
            const int jj = j + c;
            float v = 0.0f;
            if (jj != i) {
                const uint32_t key = fkey(pi * pjv[c]);
                if (key > hi) {
                    v = 1.0f;
                } else if (key >= lo) {
                    const uint32_t flat = (uint32_t)(i * NN + jj);
                    const uint32_t r = ws[WS_R];
                    for (uint32_t m = 0; m < r; ++m)
                        if (ws[WS_CH + m] == flat) { v = 1.0f; break; }
                }
            }
            vv[c] = v;
        }
        float4 o;
        o.x = vv[0]; o.y = vv[1]; o.z = vv[2]; o.w = vv[3];
        *reinterpret_cast<float4*>(out + rowbase + j) = o;
    }
}

extern "C" void kernel_launch(void* const* d_in, const int* in_sizes, int n_in,
                              void* d_out, int out_size, void* d_ws, size_t ws_size,
                              hipStream_t stream) {
    const float* p = (const float*)d_in[0];
    float* out = (float*)d_out;
    uint32_t* ws = (uint32_t*)d_ws;

    sort_kernel<<<1024, 256, 0, stream>>>(p, ws);
    select_round_kernel<1><<<1024, 512, 0, stream>>>(ws);
    select_round_kernel<2><<<1024, 512, 0, stream>>>(ws);
    select_round_kernel<3><<<1024, 512, 0, stream>>>(ws);
    finalize_enum_kernel<<<1, 512, 0, stream>>>(ws);
    mask_kernel<<<dim3(2, NN), 256, 0, stream>>>(p, out, ws);
}

// Round 15
// 325.560 us; speedup vs baseline: 1.1137x; 1.1137x over previous
//
#include <hip/hip_runtime.h>
#include <stdint.h>

#define NN 8192
#define K_ORD 262144u      // ordered top-k positions (off-diagonal, both triangles)
#define TIE_CAP 16384u

// ws layout (uint32 words):
// [0..3071]    partial counts: round r (1..3) block bx writes [(r-1)*1024 + bx]
//              (bx = probe*4 + quarter; per-probe count = sum of its 4 slots)
// [4096] hi  [4097] lo  [4098] r_ord  [4099] tie_cnt  [4100..4103] pad
// [4104..12295] sorted p values (8192 floats, desc by key)
// [12296..]    tie entries: uint2 {key, flat_idx} (12296 even -> 8B aligned)
#define WS_HI 4096
#define WS_LO 4097
#define WS_R 4098
#define WS_TIECNT 4099
#define WS_STATE0 4096
#define WS_STATEN 8
#define WS_SORT 4104
#define WS_TIE 12296

__device__ __forceinline__ uint32_t fkey(float x) {
    // order-preserving map float -> uint32 (neg: ~u, pos: u|0x80000000)
    uint32_t u = __float_as_uint(x);
    uint32_t m = (uint32_t)((int32_t)u >> 31) | 0x80000000u;
    return u ^ m;
}
__device__ __forceinline__ float inv_fkey(uint32_t k) {
    uint32_t u = (k & 0x80000000u) ? (k ^ 0x80000000u) : ~k;
    return __uint_as_float(u);
}

// ---------------------------------------------------------------------------
// Kernel 1 (R8-verbatim): brute-force rank sort of p (desc by key, ties by
// index) -> ws sorted. 1024 blocks x 256 thr; block ranks 8 elements.
__global__ void __launch_bounds__(256) sort_kernel(const float* __restrict__ p,
                                                   uint32_t* __restrict__ ws) {
    __shared__ uint32_t ks[NN];
    const int tx = threadIdx.x;
    if (blockIdx.x == 0 && tx < WS_STATEN) ws[WS_STATE0 + tx] = 0u;
    for (int t = tx; t < NN / 4; t += 256) {
        const float4 v = reinterpret_cast<const float4*>(p)[t];
        reinterpret_cast<uint4*>(ks)[t] =
            make_uint4(fkey(v.x), fkey(v.y), fkey(v.z), fkey(v.w));
    }
    __syncthreads();
    const int e = blockIdx.x * 8 + (tx >> 5);
    const int seg = tx & 31;
    const uint32_t ke = ks[e];
    uint32_t cnt = 0;
    for (int it = 0; it < 256; ++it) {
        const int j = seg + 32 * it;
        const uint32_t kj = ks[j];
        cnt += (kj > ke) ? 1u : 0u;
        cnt += (kj == ke && j < e) ? 1u : 0u;
    }
    for (int off = 16; off > 0; off >>= 1) cnt += __shfl_down(cnt, off, 32);
    if (seg == 0)
        reinterpret_cast<float*>(ws + WS_SORT)[cnt] = inv_fkey(ke);  // unique rank
}

// ---------------------------------------------------------------------------
// Partial f(T) over rows [a0, a0+2048): 4 INDEPENDENT interleaved 14-step
// chains per thread (ILP4; correctness-proven R6/R9/R13). Search space [0,8192].
__device__ uint32_t eval_count4(const float* __restrict__ ps, uint32_t T, int a0) {
    const int a = a0 + threadIdx.x * 4;
    float pa[4];
    uint32_t neg[4];
    int pos[4] = {0, 0, 0, 0};
#pragma unroll
    for (int c = 0; c < 4; ++c) {
        pa[c] = ps[a + c];
        neg[c] = __float_as_uint(pa[c]) >> 31;
    }
#pragma unroll
    for (int st = NN; st > 0; st >>= 1) {
#pragma unroll
        for (int c = 0; c < 4; ++c) {
            const int cand = pos[c] + st;
            if (cand <= NN) {
                const uint32_t pr = (fkey(pa[c] * ps[cand - 1]) > T) ? 1u : 0u;
                if (pr ^ neg[c]) pos[c] = cand;
            }
        }
    }
    uint32_t cnt = 0;
#pragma unroll
    for (int c = 0; c < 4; ++c) {
        uint32_t cc = neg[c] ? (uint32_t)(NN - pos[c]) : (uint32_t)pos[c];
        cc -= (fkey(pa[c] * pa[c]) > T) ? 1u : 0u;   // exclude diagonal pairing
        cnt += cc;
    }
    return cnt;
}

// Recompute bracket after `rounds` completed rounds (R8-proven). Per-probe
// count = sum of its 4 quarter slots (relaxed agent atomic loads).
// On exit: T* in [lo,hi], fstar = f(hi) < K.
template <int NT>
__device__ void bracket_chain(const uint32_t* __restrict__ ws, int rounds,
                              uint32_t* __restrict__ sh,
                              uint32_t& lo, uint32_t& hi, uint32_t& fstar) {
    const int tx = threadIdx.x;
    lo = 0u; hi = 0xFFFFFFFFu; fstar = 0u;
    for (int r = 0; r < rounds; ++r) {
        uint32_t flag = 1024u;
        if (tx < 256) {
            uint32_t c = 0;
#pragma unroll
            for (int q = 0; q < 4; ++q)
                c += __hip_atomic_load(&ws[r * 1024 + tx * 4 + q],
                                       __ATOMIC_RELAXED, __HIP_MEMORY_SCOPE_AGENT);
            if (c < K_ORD) flag = (uint32_t)tx;
        }
        sh[tx] = flag;
        __syncthreads();
        for (int off = NT / 2; off > 0; off >>= 1) {
            if (tx < off) sh[tx] = min(sh[tx], sh[tx + off]);
            __syncthreads();
        }
        const uint32_t cs = sh[0];   // minimal c with f(T_c) < K (exists: f(hi)<K)
        __syncthreads();
        uint32_t fsum = 0;
#pragma unroll
        for (int q = 0; q < 4; ++q)
            fsum += __hip_atomic_load(&ws[r * 1024 + cs * 4 + q],
                                      __ATOMIC_RELAXED, __HIP_MEMORY_SCOPE_AGENT);
        fstar = fsum;
        const uint64_t W = (uint64_t)(hi - lo);
        const uint32_t Tc = lo + (uint32_t)(((uint64_t)(cs + 1) * W) >> 8);
        if (cs > 0) lo = lo + (uint32_t)(((uint64_t)cs * W) >> 8) + 1u;
        hi = Tc;
    }
}

// Kernels 2-4: rounds 1-3 (R13-verbatim: ILP4 eval, plain-store partials).
template <int ROUND>
__global__ void __launch_bounds__(512) select_round_kernel(uint32_t* __restrict__ ws) {
    __shared__ float ps[NN];
    __shared__ uint32_t sh[512];
    const int tx = threadIdx.x;
    const int bx = blockIdx.x;
    for (int t = tx; t < NN / 4; t += 512)
        reinterpret_cast<float4*>(ps)[t] =
            reinterpret_cast<const float4*>(ws + WS_SORT)[t];
    __syncthreads();
    uint32_t lo, hi, fs;
    bracket_chain<512>(ws, ROUND - 1, sh, lo, hi, fs);
    const uint64_t W = (uint64_t)(hi - lo);
    const uint32_t T = lo + (uint32_t)(((uint64_t)((bx >> 2) + 1) * W) >> 8);
    const uint32_t cnt = eval_count4(ps, T, (bx & 3) * 2048);
    __syncthreads();
    sh[tx] = cnt;
    __syncthreads();
    for (int off = 256; off > 0; off >>= 1) {
        if (tx < off) sh[tx] += sh[tx + off];
        __syncthreads();
    }
    if (tx == 0) ws[(ROUND - 1) * 1024 + bx] = sh[0];   // private slot, plain store
}

// Kernel 5 (R11-verbatim): finalize after 3 rounds. Bracket <= 257 keys wide;
// whole bracket = tie class (~100-ish pairs).
__global__ void __launch_bounds__(256) finalize3_kernel(uint32_t* __restrict__ ws) {
    __shared__ uint32_t sh[256];
    uint32_t lo, hi, fs;
    bracket_chain<256>(ws, 3, sh, lo, hi, fs);
    if (threadIdx.x == 0) {
        ws[WS_HI] = hi;               // f(hi) < K
        ws[WS_LO] = lo;               // f(lo-1) >= K  (K-th key in [lo,hi])
        ws[WS_R] = K_ORD - fs;        // in-bracket slots, by (key desc, idx asc)
    }
}

// Kernel 6 (R11-verbatim): streamed 268MB mask write, plain float4 stores.
// 1.0 iff key > hi; lo <= key <= hi -> tie buffer {key, flat}.
__global__ void __launch_bounds__(256) mask_kernel(const float* __restrict__ p,
                                                   float* __restrict__ out,
                                                   uint32_t* __restrict__ ws) {
    const int tx = threadIdx.x;
    const int i = blockIdx.y;
    const int jb0 = blockIdx.x * 4096;
    const uint32_t hi = ws[WS_HI];
    const uint32_t lo = ws[WS_LO];
    const float pi = p[i];
    const size_t rowbase = (size_t)i * NN;
#pragma unroll
    for (int q = 0; q < 4; ++q) {
        const int j = jb0 + q * 1024 + tx * 4;
        const float4 pj = *reinterpret_cast<const float4*>(p + j);
        const float pjv[4] = {pj.x, pj.y, pj.z, pj.w};
        float vv[4];
#pragma unroll
        for (int c = 0; c < 4; ++c) {
            const int jj = j + c;
            float v = 0.0f;
            if (jj != i) {
                const uint32_t key = fkey(pi * pjv[c]);
                if (key > hi) {
                    v = 1.0f;
                } else if (key >= lo) {
                    const uint32_t pos = atomicAdd(&ws[WS_TIECNT], 1u);
                    if (pos < TIE_CAP)
                        reinterpret_cast<uint2*>(ws + WS_TIE)[pos] =
                            make_uint2(key, (uint32_t)(i * NN + jj));
                }
            }
            vv[c] = v;
        }
        float4 o;
        o.x = vv[0]; o.y = vv[1]; o.z = vv[2]; o.w = vv[3];
        *reinterpret_cast<float4*>(out + rowbase + j) = o;
    }
}

// Kernel 7 (R11-verbatim): among the n in-bracket entries set the top r by
// (key desc, flat idx asc) to 1.0 — exactly jax.lax.top_k's ordering.
__global__ void __launch_bounds__(256) tie_select_kernel(float* __restrict__ out,
                                                         uint32_t* __restrict__ ws) {
    uint32_t n = ws[WS_TIECNT];
    if (n > TIE_CAP) n = TIE_CAP;
    const uint32_t r = ws[WS_R];
    const uint2* buf = reinterpret_cast<const uint2*>(ws + WS_TIE);
    for (uint32_t e = threadIdx.x; e < n; e += 256) {
        const uint2 me = buf[e];
        uint32_t rank = 0;
        for (uint32_t m = 0; m < n; ++m) {
            const uint2 o = buf[m];
            rank += ((o.x > me.x) || (o.x == me.x && o.y < me.y)) ? 1u : 0u;
        }
        if (rank < r) out[me.y] = 1.0f;
    }
}

extern "C" void kernel_launch(void* const* d_in, const int* in_sizes, int n_in,
                              void* d_out, int out_size, void* d_ws, size_t ws_size,
                              hipStream_t stream) {
    const float* p = (const float*)d_in[0];
    float* out = (float*)d_out;
    uint32_t* ws = (uint32_t*)d_ws;

    sort_kernel<<<1024, 256, 0, stream>>>(p, ws);
    select_round_kernel<1><<<1024, 512, 0, stream>>>(ws);
    select_round_kernel<2><<<1024, 512, 0, stream>>>(ws);
    select_round_kernel<3><<<1024, 512, 0, stream>>>(ws);
    finalize3_kernel<<<1, 256, 0, stream>>>(ws);
    mask_kernel<<<dim3(2, NN), 256, 0, stream>>>(p, out, ws);
    tie_select_kernel<<<1, 256, 0, stream>>>(out, ws);
}